// Round 11
// baseline (209.398 us; speedup 1.0000x reference)
//
#include <hip/hip_runtime.h>
#include <math.h>

// Problem constants: B=1, D=H=W=24, N=13824, C=128, NUM_HEADS=4, hc=32, K3=27.
#define NTOK 13824
#define CCH 128
#define DD3 24
#define SCALE 0.17677669529663687f  // 32^-0.5

typedef float  f32x4  __attribute__((ext_vector_type(4)));
typedef short  s16x8  __attribute__((ext_vector_type(8)));

__device__ __forceinline__ ushort bf16_rtn(float f) {
    unsigned u = __float_as_uint(f);
    unsigned r = u + 0x7fffu + ((u >> 16) & 1u);
    return (ushort)(r >> 16);
}
__device__ __forceinline__ float bf16_f32(ushort h) {
    return __uint_as_float(((unsigned)h) << 16);
}
__device__ __forceinline__ float4 bf4_f4(ushort4 u) {
    float4 f;
    f.x = bf16_f32(u.x); f.y = bf16_f32(u.y);
    f.z = bf16_f32(u.z); f.w = bf16_f32(u.w);
    return f;
}

// Swizzled LDS element index: row n, 8-elem k-group g (bank-balanced b128 reads)
#define BSW(n, g) ((n) * 128 + ((((g) ^ ((n) & 7))) << 3))

// ---------------------------------------------------------------------------
// prep_w (x reps): wimg = per-block LDS byte image of weight segments.
// ---------------------------------------------------------------------------
__global__ __launch_bounds__(256) void prep_w(
    const float* __restrict__ Wq, const float* __restrict__ Wkv,
    const float* __restrict__ Wp, ushort* __restrict__ wimg, int reps)
{
    for (int rep = 0; rep < reps; ++rep) {
        const int i   = blockIdx.x * 256 + threadIdx.x;
        const int seg = i >> 11;
        const int r   = i & 2047;
        const int n   = r & 63;
        const int k4  = (r >> 6) * 4;
        const float* W; int ldw, scol;
        if (seg < 2)      { W = Wq;  ldw = 128; scol = seg * 64; }
        else if (seg < 6) { W = Wkv; ldw = 256; scol = (seg - 2) * 64; }
        else              { W = Wp;  ldw = 128; scol = (seg - 6) * 64; }
        ushort4 hi, lo;
        float v;
        v = W[(k4 + 0) * ldw + scol + n]; hi.x = bf16_rtn(v); lo.x = bf16_rtn(v - bf16_f32(hi.x));
        v = W[(k4 + 1) * ldw + scol + n]; hi.y = bf16_rtn(v); lo.y = bf16_rtn(v - bf16_f32(hi.y));
        v = W[(k4 + 2) * ldw + scol + n]; hi.z = bf16_rtn(v); lo.z = bf16_rtn(v - bf16_f32(hi.z));
        v = W[(k4 + 3) * ldw + scol + n]; hi.w = bf16_rtn(v); lo.w = bf16_rtn(v - bf16_f32(hi.w));
        const int g = k4 >> 3;
        const int f = seg * 16384 + BSW(n, g) + (k4 & 7);
        *(ushort4*)(wimg + f)        = hi;
        *(ushort4*)(wimg + f + 8192) = lo;
    }
}

// ---------------------------------------------------------------------------
// QKV GEMM (x reps). grid (216, 6), block 256.
// ---------------------------------------------------------------------------
__global__ __launch_bounds__(256) void qkv_fused(
    const float* __restrict__ x, const ushort* __restrict__ wimg,
    const float* __restrict__ bq, const float* __restrict__ bkv,
    float* __restrict__ qb, ushort* __restrict__ kvb, int reps)
{
    __shared__ ushort bsh[2][8192];   // 32 KB

    const int t  = threadIdx.x;
    const int y  = blockIdx.y;
    const int wv = t >> 6, l = t & 63;
    const int lm = l & 15, lk = l >> 4;
    const int row = blockIdx.x * 64 + wv * 16 + lm;
    const int ko  = lk * 8;

    for (int rep = 0; rep < reps; ++rep) {
        const char* wseg = (const char*)(wimg + y * 16384);
        #pragma unroll
        for (int p = 0; p < 8; ++p) {
            const int chunk = (wv * 8 + p) * 1024;
            __builtin_amdgcn_global_load_lds(
                (const __attribute__((address_space(1))) void*)(wseg + chunk + l * 16),
                (__attribute__((address_space(3))) void*)((char*)bsh + chunk),
                16, 0, 0);
        }

        s16x8 ah[4], al[4];
        #pragma unroll
        for (int kb = 0; kb < 4; ++kb) {
            const int k0 = kb * 32;
            const float4 a0 = *(const float4*)(x + row * 128 + k0 + ko);
            const float4 a1 = *(const float4*)(x + row * 128 + k0 + ko + 4);
            const float av[8] = {a0.x, a0.y, a0.z, a0.w, a1.x, a1.y, a1.z, a1.w};
            #pragma unroll
            for (int e = 0; e < 8; ++e) {
                const ushort hh = bf16_rtn(av[e]);
                ah[kb][e] = (short)hh;
                al[kb][e] = (short)bf16_rtn(av[e] - bf16_f32(hh));
            }
        }

        __syncthreads();

        f32x4 acc[4];
        #pragma unroll
        for (int nt = 0; nt < 4; ++nt)
            #pragma unroll
            for (int r = 0; r < 4; ++r) acc[nt][r] = 0.f;

        #pragma unroll
        for (int nt = 0; nt < 4; ++nt) {
            const int n = nt * 16 + lm;
            s16x8 bh[4], bl[4];
            #pragma unroll
            for (int kb = 0; kb < 4; ++kb) {
                const int g = kb * 4 + lk;
                bh[kb] = *(const s16x8*)(&bsh[0][BSW(n, g)]);
                bl[kb] = *(const s16x8*)(&bsh[1][BSW(n, g)]);
            }
            #pragma unroll
            for (int kb = 0; kb < 4; ++kb) {
                acc[nt] = __builtin_amdgcn_mfma_f32_16x16x32_bf16(ah[kb], bh[kb], acc[nt], 0, 0, 0);
                acc[nt] = __builtin_amdgcn_mfma_f32_16x16x32_bf16(ah[kb], bl[kb], acc[nt], 0, 0, 0);
                acc[nt] = __builtin_amdgcn_mfma_f32_16x16x32_bf16(al[kb], bh[kb], acc[nt], 0, 0, 0);
            }
        }

        const int orow0 = blockIdx.x * 64 + wv * 16 + lk * 4;
        #pragma unroll
        for (int nt = 0; nt < 4; ++nt) {
            const int col = y * 64 + nt * 16 + lm;
            if (col < 128) {
                const float b = bq[col];
                #pragma unroll
                for (int r = 0; r < 4; ++r)
                    qb[(orow0 + r) * 128 + col] = (acc[nt][r] + b) * SCALE;
            } else {
                const int c2 = col - 128;
                const float b = bkv[c2];
                #pragma unroll
                for (int r = 0; r < 4; ++r)
                    kvb[(orow0 + r) * 256 + c2] = bf16_rtn(acc[nt][r] + b);
            }
        }
        __syncthreads();   // protect LDS before next rep's DMA
    }
}

// ---------------------------------------------------------------------------
// Fused LDS-halo attention + projection (x reps).
// ---------------------------------------------------------------------------
__global__ __launch_bounds__(256) void attn_proj(
    const float4* __restrict__ qb4, const ushort4* __restrict__ kvb4,
    const ushort* __restrict__ wimg, const float* __restrict__ bp,
    float* __restrict__ out, int reps)
{
    __shared__ ushort smem[40960];    // 81920 B
    ushort4* sm4 = (ushort4*)smem;

    const int t  = threadIdx.x;
    const int b  = blockIdx.x;
    const int tw = b % 6, th = (b / 6) % 6, td = b / 36;
    const int d0 = td * 2, h0 = th * 4, w0 = tw * 4;
    const int sub = t & 31;
    const int vx0 = t >> 5;
    const int wv = t >> 6, l = t & 63;
    const int lm = l & 15, lk = l >> 4;

    for (int rep = 0; rep < reps; ++rep) {
        // ---- phase 1: stage halo ----
        #pragma unroll
        for (int p = 0; p < 36; ++p) {
            const int e = p * 256 + t;
            const int r = e >> 6;
            const int o = e & 63;
            const int a = r / 36, bb = (r / 6) % 6, c = r % 6;
            const int gd = d0 - 1 + a, gh = h0 - 1 + bb, gw = w0 - 1 + c;
            ushort4 v = {0, 0, 0, 0};
            if ((unsigned)gd < DD3 && (unsigned)gh < DD3 && (unsigned)gw < DD3)
                v = kvb4[((gd * DD3 + gh) * DD3 + gw) * 64 + o];
            sm4[r * 64 + o] = v;
        }
        __syncthreads();

        float4 aov[4];
        #pragma unroll
        for (int pass = 0; pass < 4; ++pass) {
            const int vox = pass * 8 + vx0;
            const int ld = vox >> 4, lh = (vox >> 2) & 3, lw = vox & 3;
            const int n  = ((d0 + ld) * DD3 + (h0 + lh)) * DD3 + (w0 + lw);

            const float4 q = qb4[n * 32 + sub];
            const ushort4* kbase = &sm4[(ld * 36 + lh * 6 + lw) * 64 + sub];

            float logit[27];
            #pragma unroll
            for (int i = 0; i < 3; ++i)
                #pragma unroll
                for (int j = 0; j < 3; ++j)
                    #pragma unroll
                    for (int l2 = 0; l2 < 3; ++l2) {
                        const int idx = (i * 3 + j) * 3 + l2;
                        const float4 kk = bf4_f4(kbase[(i * 36 + j * 6 + l2) * 64]);
                        float p = q.x * kk.x + q.y * kk.y + q.z * kk.z + q.w * kk.w;
                        p += __shfl_xor(p, 1);
                        p += __shfl_xor(p, 2);
                        p += __shfl_xor(p, 4);
                        logit[idx] = p;
                    }

            float mx = logit[0];
            #pragma unroll
            for (int idx = 1; idx < 27; ++idx) mx = fmaxf(mx, logit[idx]);
            float s = 0.f;
            #pragma unroll
            for (int idx = 0; idx < 27; ++idx) {
                logit[idx] = __expf(logit[idx] - mx);
                s += logit[idx];
            }
            const float inv = 1.f / s;

            float4 acc = {0.f, 0.f, 0.f, 0.f};
            #pragma unroll
            for (int i = 0; i < 3; ++i)
                #pragma unroll
                for (int j = 0; j < 3; ++j)
                    #pragma unroll
                    for (int l2 = 0; l2 < 3; ++l2) {
                        const int idx = (i * 3 + j) * 3 + l2;
                        const float4 vv = bf4_f4(kbase[(i * 36 + j * 6 + l2) * 64 + 32]);
                        acc.x += logit[idx] * vv.x;
                        acc.y += logit[idx] * vv.y;
                        acc.z += logit[idx] * vv.z;
                        acc.w += logit[idx] * vv.w;
                    }
            aov[pass].x = acc.x * inv;
            aov[pass].y = acc.y * inv;
            aov[pass].z = acc.z * inv;
            aov[pass].w = acc.w * inv;
        }

        __syncthreads();

        // ---- phase 2 staging ----
        const char* wsrc = (const char*)(wimg + 6 * 16384);
        #pragma unroll
        for (int p = 0; p < 16; ++p) {
            const int chunk = (wv * 16 + p) * 1024;
            __builtin_amdgcn_global_load_lds(
                (const __attribute__((address_space(1))) void*)(wsrc + chunk + l * 16),
                (__attribute__((address_space(3))) void*)((char*)smem + chunk),
                16, 0, 0);
        }

        #pragma unroll
        for (int p = 0; p < 4; ++p) {
            const int vox = p * 8 + vx0;
            const float4 a = aov[p];
            ushort4 hh, ll;
            hh.x = bf16_rtn(a.x); ll.x = bf16_rtn(a.x - bf16_f32(hh.x));
            hh.y = bf16_rtn(a.y); ll.y = bf16_rtn(a.y - bf16_f32(hh.y));
            hh.z = bf16_rtn(a.z); ll.z = bf16_rtn(a.z - bf16_f32(hh.z));
            hh.w = bf16_rtn(a.w); ll.w = bf16_rtn(a.w - bf16_f32(hh.w));
            const int g   = sub >> 1;
            const int idx = vox * 128 + (((g ^ (vox & 7))) << 3) + (sub & 1) * 4;
            *(ushort4*)&smem[32768 + idx] = hh;
            *(ushort4*)&smem[36864 + idx] = ll;
        }
        __syncthreads();

        // ---- phase 2 MFMA ----
        s16x8 ah[2][4], al[2][4];
        #pragma unroll
        for (int rt = 0; rt < 2; ++rt) {
            const int rowA = rt * 16 + lm;
            #pragma unroll
            for (int kb = 0; kb < 4; ++kb) {
                const int g = kb * 4 + lk;
                ah[rt][kb] = *(const s16x8*)&smem[32768 + BSW(rowA, g)];
                al[rt][kb] = *(const s16x8*)&smem[36864 + BSW(rowA, g)];
            }
        }

        f32x4 acc2[2][2];
        #pragma unroll
        for (int rt = 0; rt < 2; ++rt)
            #pragma unroll
            for (int ct = 0; ct < 2; ++ct)
                #pragma unroll
                for (int r = 0; r < 4; ++r) acc2[rt][ct][r] = 0.f;

        const int ncol = wv * 32;
        #pragma unroll
        for (int ct = 0; ct < 2; ++ct) {
            const int n  = ncol + ct * 16 + lm;
            const int hb = (n >= 64) ? 16384 : 0;
            const int nn = n & 63;
            s16x8 bh[4], bl[4];
            #pragma unroll
            for (int kb = 0; kb < 4; ++kb) {
                const int g = kb * 4 + lk;
                bh[kb] = *(const s16x8*)&smem[hb + BSW(nn, g)];
                bl[kb] = *(const s16x8*)&smem[hb + 8192 + BSW(nn, g)];
            }
            #pragma unroll
            for (int rt = 0; rt < 2; ++rt)
                #pragma unroll
                for (int kb = 0; kb < 4; ++kb) {
                    acc2[rt][ct] = __builtin_amdgcn_mfma_f32_16x16x32_bf16(ah[rt][kb], bh[kb], acc2[rt][ct], 0, 0, 0);
                    acc2[rt][ct] = __builtin_amdgcn_mfma_f32_16x16x32_bf16(ah[rt][kb], bl[kb], acc2[rt][ct], 0, 0, 0);
                    acc2[rt][ct] = __builtin_amdgcn_mfma_f32_16x16x32_bf16(al[rt][kb], bh[kb], acc2[rt][ct], 0, 0, 0);
                }
        }

        #pragma unroll
        for (int rt = 0; rt < 2; ++rt)
            #pragma unroll
            for (int ct = 0; ct < 2; ++ct) {
                const int col = ncol + ct * 16 + lm;
                const float bb = bp[col];
                #pragma unroll
                for (int r = 0; r < 4; ++r) {
                    const int vox = rt * 16 + lk * 4 + r;
                    const int ld = vox >> 4, lh = (vox >> 2) & 3, lw = vox & 3;
                    const int n  = ((d0 + ld) * DD3 + (h0 + lh)) * DD3 + (w0 + lw);
                    out[n * 128 + col] = acc2[rt][ct][r] + bb;
                }
            }
        __syncthreads();   // protect LDS before next rep's halo staging
    }
}

extern "C" void kernel_launch(void* const* d_in, const int* in_sizes, int n_in,
                              void* d_out, int out_size, void* d_ws, size_t ws_size,
                              hipStream_t stream) {
    const float* x   = (const float*)d_in[0];
    const float* Wq  = (const float*)d_in[1];
    const float* bq  = (const float*)d_in[2];
    const float* Wkv = (const float*)d_in[3];
    const float* bkv = (const float*)d_in[4];
    const float* Wp  = (const float*)d_in[5];
    const float* bp  = (const float*)d_in[6];
    float* out = (float*)d_out;

    char* ws = (char*)d_ws;
    float*  qb   = (float*)(ws);
    ushort* kvb  = (ushort*)(ws + 7077888);
    ushort* wimg = (ushort*)(ws + 14155776);

    const int REPS = 4;   // diagnostic amplification: true dur = shown / 4
    prep_w<<<64, 256, 0, stream>>>(Wq, Wkv, Wp, wimg, REPS);
    dim3 g1(NTOK / 64, 6);
    qkv_fused<<<g1, 256, 0, stream>>>(x, wimg, bq, bkv, qb, kvb, REPS);
    attn_proj<<<432, 256, 0, stream>>>((const float4*)qb, (const ushort4*)kvb,
                                       wimg, bp, out, REPS);
}

// Round 12
// 78.640 us; speedup vs baseline: 2.6627x; 2.6627x over previous
//
#include <hip/hip_runtime.h>
#include <math.h>

// Problem constants: B=1, D=H=W=24, N=13824, C=128, NUM_HEADS=4, hc=32, K3=27.
#define NTOK 13824
#define CCH 128
#define DD3 24
#define SCALE 0.17677669529663687f  // 32^-0.5

typedef float  f32x4  __attribute__((ext_vector_type(4)));
typedef short  s16x8  __attribute__((ext_vector_type(8)));

__device__ __forceinline__ ushort bf16_rtn(float f) {
    unsigned u = __float_as_uint(f);
    unsigned r = u + 0x7fffu + ((u >> 16) & 1u);
    return (ushort)(r >> 16);
}
__device__ __forceinline__ float bf16_f32(ushort h) {
    return __uint_as_float(((unsigned)h) << 16);
}
__device__ __forceinline__ float4 bf4_f4(ushort4 u) {
    float4 f;
    f.x = bf16_f32(u.x); f.y = bf16_f32(u.y);
    f.z = bf16_f32(u.z); f.w = bf16_f32(u.w);
    return f;
}

// Swizzled LDS element index: row n, 8-elem k-group g (bank-balanced b128 reads)
#define BSW(n, g) ((n) * 128 + ((((g) ^ ((n) & 7))) << 3))

// ---------------------------------------------------------------------------
// prep_w: wimg = per-block LDS byte image of weight segments
// (8 segs x [hi 8192 | lo 8192] ushorts, swizzled). 64 blocks x 256.
// ---------------------------------------------------------------------------
__global__ __launch_bounds__(256) void prep_w(
    const float* __restrict__ Wq, const float* __restrict__ Wkv,
    const float* __restrict__ Wp, ushort* __restrict__ wimg)
{
    const int i   = blockIdx.x * 256 + threadIdx.x;
    const int seg = i >> 11;
    const int r   = i & 2047;
    const int n   = r & 63;
    const int k4  = (r >> 6) * 4;
    const float* W; int ldw, scol;
    if (seg < 2)      { W = Wq;  ldw = 128; scol = seg * 64; }
    else if (seg < 6) { W = Wkv; ldw = 256; scol = (seg - 2) * 64; }
    else              { W = Wp;  ldw = 128; scol = (seg - 6) * 64; }
    ushort4 hi, lo;
    float v;
    v = W[(k4 + 0) * ldw + scol + n]; hi.x = bf16_rtn(v); lo.x = bf16_rtn(v - bf16_f32(hi.x));
    v = W[(k4 + 1) * ldw + scol + n]; hi.y = bf16_rtn(v); lo.y = bf16_rtn(v - bf16_f32(hi.y));
    v = W[(k4 + 2) * ldw + scol + n]; hi.z = bf16_rtn(v); lo.z = bf16_rtn(v - bf16_f32(hi.z));
    v = W[(k4 + 3) * ldw + scol + n]; hi.w = bf16_rtn(v); lo.w = bf16_rtn(v - bf16_f32(hi.w));
    const int g = k4 >> 3;
    const int f = seg * 16384 + BSW(n, g) + (k4 & 7);
    *(ushort4*)(wimg + f)        = hi;
    *(ushort4*)(wimg + f + 8192) = lo;
}

// ---------------------------------------------------------------------------
// QKV GEMM. grid (216, 6), block 256 (4 waves). W panel DMA'd from wimg via
// global_load_lds (16B); A = x converted to bf16 hi/lo in registers.
// ---------------------------------------------------------------------------
__global__ __launch_bounds__(256) void qkv_fused(
    const float* __restrict__ x, const ushort* __restrict__ wimg,
    const float* __restrict__ bq, const float* __restrict__ bkv,
    float* __restrict__ qb, ushort* __restrict__ kvb)
{
    __shared__ ushort bsh[2][8192];   // 32 KB

    const int t  = threadIdx.x;
    const int y  = blockIdx.y;
    const int wv = t >> 6, l = t & 63;

    const char* wseg = (const char*)(wimg + y * 16384);
    #pragma unroll
    for (int p = 0; p < 8; ++p) {
        const int chunk = (wv * 8 + p) * 1024;
        __builtin_amdgcn_global_load_lds(
            (const __attribute__((address_space(1))) void*)(wseg + chunk + l * 16),
            (__attribute__((address_space(3))) void*)((char*)bsh + chunk),
            16, 0, 0);
    }

    const int lm = l & 15, lk = l >> 4;
    const int row = blockIdx.x * 64 + wv * 16 + lm;
    const int ko  = lk * 8;

    s16x8 ah[4], al[4];
    #pragma unroll
    for (int kb = 0; kb < 4; ++kb) {
        const int k0 = kb * 32;
        const float4 a0 = *(const float4*)(x + row * 128 + k0 + ko);
        const float4 a1 = *(const float4*)(x + row * 128 + k0 + ko + 4);
        const float av[8] = {a0.x, a0.y, a0.z, a0.w, a1.x, a1.y, a1.z, a1.w};
        #pragma unroll
        for (int e = 0; e < 8; ++e) {
            const ushort hh = bf16_rtn(av[e]);
            ah[kb][e] = (short)hh;
            al[kb][e] = (short)bf16_rtn(av[e] - bf16_f32(hh));
        }
    }

    __syncthreads();

    f32x4 acc[4];
    #pragma unroll
    for (int nt = 0; nt < 4; ++nt)
        #pragma unroll
        for (int r = 0; r < 4; ++r) acc[nt][r] = 0.f;

    #pragma unroll
    for (int nt = 0; nt < 4; ++nt) {
        const int n = nt * 16 + lm;
        s16x8 bh[4], bl[4];
        #pragma unroll
        for (int kb = 0; kb < 4; ++kb) {
            const int g = kb * 4 + lk;
            bh[kb] = *(const s16x8*)(&bsh[0][BSW(n, g)]);
            bl[kb] = *(const s16x8*)(&bsh[1][BSW(n, g)]);
        }
        #pragma unroll
        for (int kb = 0; kb < 4; ++kb) {
            acc[nt] = __builtin_amdgcn_mfma_f32_16x16x32_bf16(ah[kb], bh[kb], acc[nt], 0, 0, 0);
            acc[nt] = __builtin_amdgcn_mfma_f32_16x16x32_bf16(ah[kb], bl[kb], acc[nt], 0, 0, 0);
            acc[nt] = __builtin_amdgcn_mfma_f32_16x16x32_bf16(al[kb], bh[kb], acc[nt], 0, 0, 0);
        }
    }

    const int orow0 = blockIdx.x * 64 + wv * 16 + lk * 4;
    #pragma unroll
    for (int nt = 0; nt < 4; ++nt) {
        const int col = y * 64 + nt * 16 + lm;
        if (col < 128) {
            const float b = bq[col];
            #pragma unroll
            for (int r = 0; r < 4; ++r)
                qb[(orow0 + r) * 128 + col] = (acc[nt][r] + b) * SCALE;
        } else {
            const int c2 = col - 128;
            const float b = bkv[c2];
            #pragma unroll
            for (int r = 0; r < 4; ++r)
                kvb[(orow0 + r) * 256 + c2] = bf16_rtn(acc[nt][r] + b);
        }
    }
}

// ---------------------------------------------------------------------------
// Fused LDS-halo attention + projection. 512 threads (8 waves), grid 432.
// Phase 1: 2x4x4 tile, 4x6x6 halo (zero-filled OOB); 2 passes x 16 voxels.
// Phase 2: reuse LDS: Wp image (64 KB) DMA + swizzled bf16 ao (16 KB);
//          8 waves x 16 output cols MFMA projection.
// __launch_bounds__(512,4): VGPR<=128 so 2 blocks (16 waves) fit per CU.
// ---------------------------------------------------------------------------
__global__ __launch_bounds__(512, 4) void attn_proj(
    const float4* __restrict__ qb4, const ushort4* __restrict__ kvb4,
    const ushort* __restrict__ wimg, const float* __restrict__ bp,
    float* __restrict__ out)
{
    __shared__ ushort smem[40960];    // 81920 B
    ushort4* sm4 = (ushort4*)smem;

    const int t  = threadIdx.x;
    const int b  = blockIdx.x;         // 432 tiles: 12 x 6 x 6
    const int tw = b % 6, th = (b / 6) % 6, td = b / 36;
    const int d0 = td * 2, h0 = th * 4, w0 = tw * 4;

    // ---- phase 1: stage halo (144 rows x 512 B), zero-fill OOB ----
    #pragma unroll
    for (int p = 0; p < 18; ++p) {
        const int e = p * 512 + t;
        const int r = e >> 6;
        const int o = e & 63;
        const int a = r / 36, bb = (r / 6) % 6, c = r % 6;
        const int gd = d0 - 1 + a, gh = h0 - 1 + bb, gw = w0 - 1 + c;
        ushort4 v = {0, 0, 0, 0};
        if ((unsigned)gd < DD3 && (unsigned)gh < DD3 && (unsigned)gw < DD3)
            v = kvb4[((gd * DD3 + gh) * DD3 + gw) * 64 + o];
        sm4[r * 64 + o] = v;
    }
    __syncthreads();

    const int sub = t & 31;
    const int vx0 = t >> 5;            // 0..15
    float4 aov[2];

    #pragma unroll
    for (int pass = 0; pass < 2; ++pass) {
        const int vox = pass * 16 + vx0;
        const int ld = vox >> 4, lh = (vox >> 2) & 3, lw = vox & 3;
        const int n  = ((d0 + ld) * DD3 + (h0 + lh)) * DD3 + (w0 + lw);

        const float4 q = qb4[n * 32 + sub];
        const ushort4* kbase = &sm4[(ld * 36 + lh * 6 + lw) * 64 + sub];

        float logit[27];
        #pragma unroll
        for (int i = 0; i < 3; ++i)
            #pragma unroll
            for (int j = 0; j < 3; ++j)
                #pragma unroll
                for (int l2 = 0; l2 < 3; ++l2) {
                    const int idx = (i * 3 + j) * 3 + l2;
                    const float4 kk = bf4_f4(kbase[(i * 36 + j * 6 + l2) * 64]);
                    float p = q.x * kk.x + q.y * kk.y + q.z * kk.z + q.w * kk.w;
                    p += __shfl_xor(p, 1);
                    p += __shfl_xor(p, 2);
                    p += __shfl_xor(p, 4);
                    logit[idx] = p;
                }

        // tree max (depth ~5 instead of 26-chain)
        float m0 = logit[0];
        {
            float t1[14];
            #pragma unroll
            for (int k = 0; k < 13; ++k) t1[k] = fmaxf(logit[2 * k], logit[2 * k + 1]);
            t1[13] = logit[26];
            float t2[7];
            #pragma unroll
            for (int k = 0; k < 7; ++k) t2[k] = fmaxf(t1[2 * k], t1[2 * k + 1]);
            float t3a = fmaxf(t2[0], t2[1]), t3b = fmaxf(t2[2], t2[3]);
            float t3c = fmaxf(t2[4], t2[5]);
            m0 = fmaxf(fmaxf(t3a, t3b), fmaxf(t3c, t2[6]));
        }
        float s = 0.f;
        {
            float e[27];
            #pragma unroll
            for (int idx = 0; idx < 27; ++idx) e[idx] = __expf(logit[idx] - m0);
            #pragma unroll
            for (int idx = 0; idx < 27; ++idx) logit[idx] = e[idx];
            float t1[14];
            #pragma unroll
            for (int k = 0; k < 13; ++k) t1[k] = e[2 * k] + e[2 * k + 1];
            t1[13] = e[26];
            float t2[7];
            #pragma unroll
            for (int k = 0; k < 7; ++k) t2[k] = t1[2 * k] + t1[2 * k + 1];
            s = ((t2[0] + t2[1]) + (t2[2] + t2[3])) + ((t2[4] + t2[5]) + t2[6]);
        }
        const float inv = 1.f / s;

        float4 acc = {0.f, 0.f, 0.f, 0.f};
        #pragma unroll
        for (int i = 0; i < 3; ++i)
            #pragma unroll
            for (int j = 0; j < 3; ++j)
                #pragma unroll
                for (int l2 = 0; l2 < 3; ++l2) {
                    const int idx = (i * 3 + j) * 3 + l2;
                    const float4 vv = bf4_f4(kbase[(i * 36 + j * 6 + l2) * 64 + 32]);
                    acc.x += logit[idx] * vv.x;
                    acc.y += logit[idx] * vv.y;
                    acc.z += logit[idx] * vv.z;
                    acc.w += logit[idx] * vv.w;
                }
        aov[pass].x = acc.x * inv;
        aov[pass].y = acc.y * inv;
        aov[pass].z = acc.z * inv;
        aov[pass].w = acc.w * inv;
    }

    __syncthreads();   // all waves done reading halo

    // ---- phase 2 staging ----
    const int wv = t >> 6, l = t & 63;

    // (a) DMA Wp image: wimg segs 6,7 -> smem bytes [0, 65536)
    const char* wsrc = (const char*)(wimg + 6 * 16384);
    #pragma unroll
    for (int p = 0; p < 8; ++p) {
        const int chunk = (wv * 8 + p) * 1024;
        __builtin_amdgcn_global_load_lds(
            (const __attribute__((address_space(1))) void*)(wsrc + chunk + l * 16),
            (__attribute__((address_space(3))) void*)((char*)smem + chunk),
            16, 0, 0);
    }

    // (b) ao -> LDS bf16 hi/lo, swizzled. AO_H ushort idx 32768, AO_L 36864.
    #pragma unroll
    for (int p = 0; p < 2; ++p) {
        const int vox = p * 16 + vx0;
        const float4 a = aov[p];
        ushort4 hh, ll;
        hh.x = bf16_rtn(a.x); ll.x = bf16_rtn(a.x - bf16_f32(hh.x));
        hh.y = bf16_rtn(a.y); ll.y = bf16_rtn(a.y - bf16_f32(hh.y));
        hh.z = bf16_rtn(a.z); ll.z = bf16_rtn(a.z - bf16_f32(hh.z));
        hh.w = bf16_rtn(a.w); ll.w = bf16_rtn(a.w - bf16_f32(hh.w));
        const int g   = sub >> 1;
        const int idx = vox * 128 + (((g ^ (vox & 7))) << 3) + (sub & 1) * 4;
        *(ushort4*)&smem[32768 + idx] = hh;
        *(ushort4*)&smem[36864 + idx] = ll;
    }
    __syncthreads();

    // ---- phase 2 MFMA: [32 x 128] @ [128 x 128], 16 cols per wave ----
    const int lm = l & 15, lk = l >> 4;
    const int ncol = wv * 16;                 // this wave's output col tile
    const int nn = ncol >= 64 ? ncol - 64 : ncol;
    const int hb = ncol >= 64 ? 16384 : 0;

    // B fragments for this wave's col tile
    s16x8 bh[4], bl[4];
    #pragma unroll
    for (int kb = 0; kb < 4; ++kb) {
        const int g = kb * 4 + lk;
        bh[kb] = *(const s16x8*)&smem[hb + BSW(nn + lm, g)];
        bl[kb] = *(const s16x8*)&smem[hb + 8192 + BSW(nn + lm, g)];
    }

    f32x4 acc2[2];
    #pragma unroll
    for (int rt = 0; rt < 2; ++rt)
        #pragma unroll
        for (int r = 0; r < 4; ++r) acc2[rt][r] = 0.f;

    #pragma unroll
    for (int rt = 0; rt < 2; ++rt) {
        const int rowA = rt * 16 + lm;
        s16x8 ah[4], al[4];
        #pragma unroll
        for (int kb = 0; kb < 4; ++kb) {
            const int g = kb * 4 + lk;
            ah[kb] = *(const s16x8*)&smem[32768 + BSW(rowA, g)];
            al[kb] = *(const s16x8*)&smem[36864 + BSW(rowA, g)];
        }
        #pragma unroll
        for (int kb = 0; kb < 4; ++kb) {
            acc2[rt] = __builtin_amdgcn_mfma_f32_16x16x32_bf16(ah[kb], bh[kb], acc2[rt], 0, 0, 0);
            acc2[rt] = __builtin_amdgcn_mfma_f32_16x16x32_bf16(ah[kb], bl[kb], acc2[rt], 0, 0, 0);
            acc2[rt] = __builtin_amdgcn_mfma_f32_16x16x32_bf16(al[kb], bh[kb], acc2[rt], 0, 0, 0);
        }
    }

    #pragma unroll
    for (int rt = 0; rt < 2; ++rt) {
        const int col = ncol + lm;
        const float bb = bp[col];
        #pragma unroll
        for (int r = 0; r < 4; ++r) {
            const int vox = rt * 16 + lk * 4 + r;
            const int ld = vox >> 4, lh = (vox >> 2) & 3, lw = vox & 3;
            const int n  = ((d0 + ld) * DD3 + (h0 + lh)) * DD3 + (w0 + lw);
            out[n * 128 + col] = acc2[rt][r] + bb;
        }
    }
}

extern "C" void kernel_launch(void* const* d_in, const int* in_sizes, int n_in,
                              void* d_out, int out_size, void* d_ws, size_t ws_size,
                              hipStream_t stream) {
    const float* x   = (const float*)d_in[0];
    const float* Wq  = (const float*)d_in[1];
    const float* bq  = (const float*)d_in[2];
    const float* Wkv = (const float*)d_in[3];
    const float* bkv = (const float*)d_in[4];
    const float* Wp  = (const float*)d_in[5];
    const float* bp  = (const float*)d_in[6];
    float* out = (float*)d_out;

    char* ws = (char*)d_ws;
    float*  qb   = (float*)(ws);
    ushort* kvb  = (ushort*)(ws + 7077888);
    ushort* wimg = (ushort*)(ws + 14155776);

    prep_w<<<64, 256, 0, stream>>>(Wq, Wkv, Wp, wimg);
    dim3 g1(NTOK / 64, 6);
    qkv_fused<<<g1, 256, 0, stream>>>(x, wimg, bq, bkv, qb, kvb);
    attn_proj<<<432, 512, 0, stream>>>((const float4*)qb, (const ushort4*)kvb,
                                       wimg, bp, out);
}

// Round 13
// 60.474 us; speedup vs baseline: 3.4626x; 1.3004x over previous
//
#include <hip/hip_runtime.h>
#include <math.h>

// Problem constants: B=1, D=H=W=24, N=13824, C=128, NUM_HEADS=4, hc=32, K3=27.
#define NTOK 13824
#define CCH 128
#define DD3 24
#define SCALE 0.17677669529663687f  // 32^-0.5

typedef float  f32x4  __attribute__((ext_vector_type(4)));
typedef short  s16x8  __attribute__((ext_vector_type(8)));

__device__ __forceinline__ ushort bf16_rtn(float f) {
    unsigned u = __float_as_uint(f);
    unsigned r = u + 0x7fffu + ((u >> 16) & 1u);
    return (ushort)(r >> 16);
}
__device__ __forceinline__ float bf16_f32(ushort h) {
    return __uint_as_float(((unsigned)h) << 16);
}
__device__ __forceinline__ float4 bf4_f4(ushort4 u) {
    float4 f;
    f.x = bf16_f32(u.x); f.y = bf16_f32(u.y);
    f.z = bf16_f32(u.z); f.w = bf16_f32(u.w);
    return f;
}

// Swizzled LDS element index: row n, 8-elem k-group g (bank-balanced b128 reads)
#define BSW(n, g) ((n) * 128 + ((((g) ^ ((n) & 7))) << 3))

// ---------------------------------------------------------------------------
// prep_w: wimg = per-block LDS byte image of weight segments
// (8 segs x [hi 8192 | lo 8192] ushorts, swizzled). 64 blocks x 256.
// ---------------------------------------------------------------------------
__global__ __launch_bounds__(256) void prep_w(
    const float* __restrict__ Wq, const float* __restrict__ Wkv,
    const float* __restrict__ Wp, ushort* __restrict__ wimg)
{
    const int i   = blockIdx.x * 256 + threadIdx.x;
    const int seg = i >> 11;
    const int r   = i & 2047;
    const int n   = r & 63;
    const int k4  = (r >> 6) * 4;
    const float* W; int ldw, scol;
    if (seg < 2)      { W = Wq;  ldw = 128; scol = seg * 64; }
    else if (seg < 6) { W = Wkv; ldw = 256; scol = (seg - 2) * 64; }
    else              { W = Wp;  ldw = 128; scol = (seg - 6) * 64; }
    ushort4 hi, lo;
    float v;
    v = W[(k4 + 0) * ldw + scol + n]; hi.x = bf16_rtn(v); lo.x = bf16_rtn(v - bf16_f32(hi.x));
    v = W[(k4 + 1) * ldw + scol + n]; hi.y = bf16_rtn(v); lo.y = bf16_rtn(v - bf16_f32(hi.y));
    v = W[(k4 + 2) * ldw + scol + n]; hi.z = bf16_rtn(v); lo.z = bf16_rtn(v - bf16_f32(hi.z));
    v = W[(k4 + 3) * ldw + scol + n]; hi.w = bf16_rtn(v); lo.w = bf16_rtn(v - bf16_f32(hi.w));
    const int g = k4 >> 3;
    const int f = seg * 16384 + BSW(n, g) + (k4 & 7);
    *(ushort4*)(wimg + f)        = hi;
    *(ushort4*)(wimg + f + 8192) = lo;
}

// ---------------------------------------------------------------------------
// QKV GEMM. grid (216, 6), block 256 (4 waves). W panel DMA'd from wimg via
// global_load_lds (16B); A = x converted to bf16 hi/lo in registers.
// ---------------------------------------------------------------------------
__global__ __launch_bounds__(256) void qkv_fused(
    const float* __restrict__ x, const ushort* __restrict__ wimg,
    const float* __restrict__ bq, const float* __restrict__ bkv,
    float* __restrict__ qb, ushort* __restrict__ kvb)
{
    __shared__ ushort bsh[2][8192];   // 32 KB

    const int t  = threadIdx.x;
    const int y  = blockIdx.y;
    const int wv = t >> 6, l = t & 63;

    const char* wseg = (const char*)(wimg + y * 16384);
    #pragma unroll
    for (int p = 0; p < 8; ++p) {
        const int chunk = (wv * 8 + p) * 1024;
        __builtin_amdgcn_global_load_lds(
            (const __attribute__((address_space(1))) void*)(wseg + chunk + l * 16),
            (__attribute__((address_space(3))) void*)((char*)bsh + chunk),
            16, 0, 0);
    }

    const int lm = l & 15, lk = l >> 4;
    const int row = blockIdx.x * 64 + wv * 16 + lm;
    const int ko  = lk * 8;

    s16x8 ah[4], al[4];
    #pragma unroll
    for (int kb = 0; kb < 4; ++kb) {
        const int k0 = kb * 32;
        const float4 a0 = *(const float4*)(x + row * 128 + k0 + ko);
        const float4 a1 = *(const float4*)(x + row * 128 + k0 + ko + 4);
        const float av[8] = {a0.x, a0.y, a0.z, a0.w, a1.x, a1.y, a1.z, a1.w};
        #pragma unroll
        for (int e = 0; e < 8; ++e) {
            const ushort hh = bf16_rtn(av[e]);
            ah[kb][e] = (short)hh;
            al[kb][e] = (short)bf16_rtn(av[e] - bf16_f32(hh));
        }
    }

    __syncthreads();

    f32x4 acc[4];
    #pragma unroll
    for (int nt = 0; nt < 4; ++nt)
        #pragma unroll
        for (int r = 0; r < 4; ++r) acc[nt][r] = 0.f;

    #pragma unroll
    for (int nt = 0; nt < 4; ++nt) {
        const int n = nt * 16 + lm;
        s16x8 bh[4], bl[4];
        #pragma unroll
        for (int kb = 0; kb < 4; ++kb) {
            const int g = kb * 4 + lk;
            bh[kb] = *(const s16x8*)(&bsh[0][BSW(n, g)]);
            bl[kb] = *(const s16x8*)(&bsh[1][BSW(n, g)]);
        }
        #pragma unroll
        for (int kb = 0; kb < 4; ++kb) {
            acc[nt] = __builtin_amdgcn_mfma_f32_16x16x32_bf16(ah[kb], bh[kb], acc[nt], 0, 0, 0);
            acc[nt] = __builtin_amdgcn_mfma_f32_16x16x32_bf16(ah[kb], bl[kb], acc[nt], 0, 0, 0);
            acc[nt] = __builtin_amdgcn_mfma_f32_16x16x32_bf16(al[kb], bh[kb], acc[nt], 0, 0, 0);
        }
    }

    const int orow0 = blockIdx.x * 64 + wv * 16 + lk * 4;
    #pragma unroll
    for (int nt = 0; nt < 4; ++nt) {
        const int col = y * 64 + nt * 16 + lm;
        if (col < 128) {
            const float b = bq[col];
            #pragma unroll
            for (int r = 0; r < 4; ++r)
                qb[(orow0 + r) * 128 + col] = (acc[nt][r] + b) * SCALE;
        } else {
            const int c2 = col - 128;
            const float b = bkv[c2];
            #pragma unroll
            for (int r = 0; r < 4; ++r)
                kvb[(orow0 + r) * 256 + c2] = bf16_rtn(acc[nt][r] + b);
        }
    }
}

// ---------------------------------------------------------------------------
// LDS-halo 27-neighbor attention. 512 thr, grid 864 (6w x 12h x 12d tiles).
// Tile 2x2x4 voxels; halo 4x4x6 = 96 kv rows x 512 B = 48 KB LDS (zero-fill
// OOB == reference zero-padding; no bounds checks in hot loop).
// 1 voxel per 32-lane group, single pass. NO VGPR cap (R12 lesson: capping
// to 64 spilled 146 MB of scratch). Emits ao as bf16 hi/lo.
// ---------------------------------------------------------------------------
__global__ __launch_bounds__(512) void attn3d(
    const float4* __restrict__ qb4, const ushort4* __restrict__ kvb4,
    ushort4* __restrict__ aoh, ushort4* __restrict__ aol)
{
    __shared__ ushort4 sm4[96 * 64];   // 49152 B

    const int t  = threadIdx.x;
    const int b  = blockIdx.x;          // 864 tiles: 12d x 12h x 6w
    const int tw = b % 6, th = (b / 6) % 12, td = b / 72;
    const int d0 = td * 2, h0 = th * 2, w0 = tw * 4;

    // ---- stage halo (96 rows x 512 B), zero-fill OOB ----
    #pragma unroll
    for (int p = 0; p < 12; ++p) {
        const int e = p * 512 + t;          // 0..6143 (8B chunks)
        const int r = e >> 6;               // halo row 0..95
        const int o = e & 63;
        const int a = r / 24, bb = (r / 6) % 4, c = r % 6;
        const int gd = d0 - 1 + a, gh = h0 - 1 + bb, gw = w0 - 1 + c;
        ushort4 v = {0, 0, 0, 0};
        if ((unsigned)gd < DD3 && (unsigned)gh < DD3 && (unsigned)gw < DD3)
            v = kvb4[((gd * DD3 + gh) * DD3 + gw) * 64 + o];
        sm4[r * 64 + o] = v;
    }
    __syncthreads();

    const int sub = t & 31;
    const int vox = t >> 5;                 // 0..15
    const int ld = vox >> 3, lh = (vox >> 2) & 1, lw = vox & 3;
    const int n  = ((d0 + ld) * DD3 + (h0 + lh)) * DD3 + (w0 + lw);

    const float4 q = qb4[n * 32 + sub];
    const ushort4* kbase = &sm4[(ld * 24 + lh * 6 + lw) * 64 + sub];

    float logit[27];
    #pragma unroll
    for (int i = 0; i < 3; ++i)
        #pragma unroll
        for (int j = 0; j < 3; ++j)
            #pragma unroll
            for (int l2 = 0; l2 < 3; ++l2) {
                const int idx = (i * 3 + j) * 3 + l2;
                const float4 kk = bf4_f4(kbase[(i * 24 + j * 6 + l2) * 64]);
                float p = q.x * kk.x + q.y * kk.y + q.z * kk.z + q.w * kk.w;
                p += __shfl_xor(p, 1);
                p += __shfl_xor(p, 2);
                p += __shfl_xor(p, 4);
                logit[idx] = p;
            }

    // tree max
    float m0;
    {
        float t1[14];
        #pragma unroll
        for (int k = 0; k < 13; ++k) t1[k] = fmaxf(logit[2 * k], logit[2 * k + 1]);
        t1[13] = logit[26];
        float t2[7];
        #pragma unroll
        for (int k = 0; k < 7; ++k) t2[k] = fmaxf(t1[2 * k], t1[2 * k + 1]);
        m0 = fmaxf(fmaxf(fmaxf(t2[0], t2[1]), fmaxf(t2[2], t2[3])),
                   fmaxf(fmaxf(t2[4], t2[5]), t2[6]));
    }
    float s;
    {
        #pragma unroll
        for (int idx = 0; idx < 27; ++idx) logit[idx] = __expf(logit[idx] - m0);
        float t1[14];
        #pragma unroll
        for (int k = 0; k < 13; ++k) t1[k] = logit[2 * k] + logit[2 * k + 1];
        t1[13] = logit[26];
        float t2[7];
        #pragma unroll
        for (int k = 0; k < 7; ++k) t2[k] = t1[2 * k] + t1[2 * k + 1];
        s = ((t2[0] + t2[1]) + (t2[2] + t2[3])) + ((t2[4] + t2[5]) + t2[6]);
    }
    const float inv = 1.f / s;

    float4 acc = {0.f, 0.f, 0.f, 0.f};
    #pragma unroll
    for (int i = 0; i < 3; ++i)
        #pragma unroll
        for (int j = 0; j < 3; ++j)
            #pragma unroll
            for (int l2 = 0; l2 < 3; ++l2) {
                const int idx = (i * 3 + j) * 3 + l2;
                const float4 vv = bf4_f4(kbase[(i * 24 + j * 6 + l2) * 64 + 32]);
                acc.x += logit[idx] * vv.x;
                acc.y += logit[idx] * vv.y;
                acc.z += logit[idx] * vv.z;
                acc.w += logit[idx] * vv.w;
            }
    acc.x *= inv; acc.y *= inv; acc.z *= inv; acc.w *= inv;

    ushort4 hh4, ll4;
    hh4.x = bf16_rtn(acc.x); ll4.x = bf16_rtn(acc.x - bf16_f32(hh4.x));
    hh4.y = bf16_rtn(acc.y); ll4.y = bf16_rtn(acc.y - bf16_f32(hh4.y));
    hh4.z = bf16_rtn(acc.z); ll4.z = bf16_rtn(acc.z - bf16_f32(hh4.z));
    hh4.w = bf16_rtn(acc.w); ll4.w = bf16_rtn(acc.w - bf16_f32(hh4.w));
    aoh[n * 32 + sub] = hh4;
    aol[n * 32 + sub] = ll4;
}

// ---------------------------------------------------------------------------
// Projection. grid (216, 2), block 256. Wp panel DMA'd from wimg segs 6,7.
// ---------------------------------------------------------------------------
__global__ __launch_bounds__(256) void proj_fused(
    const ushort* __restrict__ aoh, const ushort* __restrict__ aol,
    const ushort* __restrict__ wimg,
    const float* __restrict__ bp, float* __restrict__ out)
{
    __shared__ ushort bsh[2][8192];   // 32 KB

    const int t  = threadIdx.x;
    const int wv = t >> 6, l = t & 63;

    const char* wseg = (const char*)(wimg + (6 + blockIdx.y) * 16384);
    #pragma unroll
    for (int p = 0; p < 8; ++p) {
        const int chunk = (wv * 8 + p) * 1024;
        __builtin_amdgcn_global_load_lds(
            (const __attribute__((address_space(1))) void*)(wseg + chunk + l * 16),
            (__attribute__((address_space(3))) void*)((char*)bsh + chunk),
            16, 0, 0);
    }

    const int lm = l & 15, lk = l >> 4;
    const int row = blockIdx.x * 64 + wv * 16 + lm;
    const int ko  = lk * 8;

    s16x8 ah[4], al[4];
    #pragma unroll
    for (int kb = 0; kb < 4; ++kb) {
        ah[kb] = *(const s16x8*)(aoh + row * 128 + kb * 32 + ko);
        al[kb] = *(const s16x8*)(aol + row * 128 + kb * 32 + ko);
    }

    __syncthreads();

    f32x4 acc[4];
    #pragma unroll
    for (int nt = 0; nt < 4; ++nt)
        #pragma unroll
        for (int r = 0; r < 4; ++r) acc[nt][r] = 0.f;

    #pragma unroll
    for (int nt = 0; nt < 4; ++nt) {
        const int n = nt * 16 + lm;
        s16x8 bh[4], bl[4];
        #pragma unroll
        for (int kb = 0; kb < 4; ++kb) {
            const int g = kb * 4 + lk;
            bh[kb] = *(const s16x8*)(&bsh[0][BSW(n, g)]);
            bl[kb] = *(const s16x8*)(&bsh[1][BSW(n, g)]);
        }
        #pragma unroll
        for (int kb = 0; kb < 4; ++kb) {
            acc[nt] = __builtin_amdgcn_mfma_f32_16x16x32_bf16(ah[kb], bh[kb], acc[nt], 0, 0, 0);
            acc[nt] = __builtin_amdgcn_mfma_f32_16x16x32_bf16(ah[kb], bl[kb], acc[nt], 0, 0, 0);
            acc[nt] = __builtin_amdgcn_mfma_f32_16x16x32_bf16(al[kb], bh[kb], acc[nt], 0, 0, 0);
        }
    }

    const int orow0 = blockIdx.x * 64 + wv * 16 + lk * 4;
    #pragma unroll
    for (int nt = 0; nt < 4; ++nt) {
        const int col = blockIdx.y * 64 + nt * 16 + lm;
        const float b = bp[col];
        #pragma unroll
        for (int r = 0; r < 4; ++r)
            out[(orow0 + r) * 128 + col] = acc[nt][r] + b;
    }
}

extern "C" void kernel_launch(void* const* d_in, const int* in_sizes, int n_in,
                              void* d_out, int out_size, void* d_ws, size_t ws_size,
                              hipStream_t stream) {
    const float* x   = (const float*)d_in[0];
    const float* Wq  = (const float*)d_in[1];
    const float* bq  = (const float*)d_in[2];
    const float* Wkv = (const float*)d_in[3];
    const float* bkv = (const float*)d_in[4];
    const float* Wp  = (const float*)d_in[5];
    const float* bp  = (const float*)d_in[6];
    float* out = (float*)d_out;

    // workspace: qb@0, kvb@7,077,888, aoh@14,155,776, aol@17,694,720,
    //            wimg@21,233,664
    char* ws = (char*)d_ws;
    float*  qb   = (float*)(ws);
    ushort* kvb  = (ushort*)(ws + 7077888);
    ushort* aoh  = (ushort*)(ws + 14155776);
    ushort* aol  = (ushort*)(ws + 17694720);
    ushort* wimg = (ushort*)(ws + 21233664);

    prep_w<<<64, 256, 0, stream>>>(Wq, Wkv, Wp, wimg);
    dim3 g1(NTOK / 64, 6);
    qkv_fused<<<g1, 256, 0, stream>>>(x, wimg, bq, bkv, qb, kvb);
    attn3d<<<864, 512, 0, stream>>>((const float4*)qb, (const ushort4*)kvb,
                                    (ushort4*)aoh, (ushort4*)aol);
    dim3 g2(NTOK / 64, 2);
    proj_fused<<<g2, 256, 0, stream>>>(aoh, aol, wimg, bp, out);
}

// Round 14
// 47.171 us; speedup vs baseline: 4.4391x; 1.2820x over previous
//
#include <hip/hip_runtime.h>
#include <math.h>

// Problem constants: B=1, D=H=W=24, N=13824, C=128, NUM_HEADS=4, hc=32, K3=27.
#define NTOK 13824
#define CCH 128
#define DD3 24
#define SCALE 0.17677669529663687f  // 32^-0.5
#define HSTRIDE 136                 // ushorts per halo row (272B = 256B + 16B pad)

typedef float  f32x4  __attribute__((ext_vector_type(4)));
typedef short  s16x8  __attribute__((ext_vector_type(8)));

__device__ __forceinline__ ushort bf16_rtn(float f) {
    unsigned u = __float_as_uint(f);
    unsigned r = u + 0x7fffu + ((u >> 16) & 1u);
    return (ushort)(r >> 16);
}
__device__ __forceinline__ float bf16_f32(ushort h) {
    return __uint_as_float(((unsigned)h) << 16);
}

// Swizzled LDS element index: row n, 8-elem k-group g (bank-balanced b128 reads)
#define BSW(n, g) ((n) * 128 + ((((g) ^ ((n) & 7))) << 3))

// ---------------------------------------------------------------------------
// prep_w: wimg = per-block LDS byte image of weight segments
// (8 segs x [hi 8192 | lo 8192] ushorts, swizzled). 64 blocks x 256.
// ---------------------------------------------------------------------------
__global__ __launch_bounds__(256) void prep_w(
    const float* __restrict__ Wq, const float* __restrict__ Wkv,
    const float* __restrict__ Wp, ushort* __restrict__ wimg)
{
    const int i   = blockIdx.x * 256 + threadIdx.x;
    const int seg = i >> 11;
    const int r   = i & 2047;
    const int n   = r & 63;
    const int k4  = (r >> 6) * 4;
    const float* W; int ldw, scol;
    if (seg < 2)      { W = Wq;  ldw = 128; scol = seg * 64; }
    else if (seg < 6) { W = Wkv; ldw = 256; scol = (seg - 2) * 64; }
    else              { W = Wp;  ldw = 128; scol = (seg - 6) * 64; }
    ushort4 hi, lo;
    float v;
    v = W[(k4 + 0) * ldw + scol + n]; hi.x = bf16_rtn(v); lo.x = bf16_rtn(v - bf16_f32(hi.x));
    v = W[(k4 + 1) * ldw + scol + n]; hi.y = bf16_rtn(v); lo.y = bf16_rtn(v - bf16_f32(hi.y));
    v = W[(k4 + 2) * ldw + scol + n]; hi.z = bf16_rtn(v); lo.z = bf16_rtn(v - bf16_f32(hi.z));
    v = W[(k4 + 3) * ldw + scol + n]; hi.w = bf16_rtn(v); lo.w = bf16_rtn(v - bf16_f32(hi.w));
    const int g = k4 >> 3;
    const int f = seg * 16384 + BSW(n, g) + (k4 & 7);
    *(ushort4*)(wimg + f)        = hi;
    *(ushort4*)(wimg + f + 8192) = lo;
}

// ---------------------------------------------------------------------------
// QKV GEMM. grid (216, 6), block 256 (4 waves). W panel DMA'd from wimg via
// global_load_lds (16B); A = x converted to bf16 hi/lo in registers.
// ---------------------------------------------------------------------------
__global__ __launch_bounds__(256) void qkv_fused(
    const float* __restrict__ x, const ushort* __restrict__ wimg,
    const float* __restrict__ bq, const float* __restrict__ bkv,
    float* __restrict__ qb, ushort* __restrict__ kvb)
{
    __shared__ ushort bsh[2][8192];   // 32 KB

    const int t  = threadIdx.x;
    const int y  = blockIdx.y;
    const int wv = t >> 6, l = t & 63;

    const char* wseg = (const char*)(wimg + y * 16384);
    #pragma unroll
    for (int p = 0; p < 8; ++p) {
        const int chunk = (wv * 8 + p) * 1024;
        __builtin_amdgcn_global_load_lds(
            (const __attribute__((address_space(1))) void*)(wseg + chunk + l * 16),
            (__attribute__((address_space(3))) void*)((char*)bsh + chunk),
            16, 0, 0);
    }

    const int lm = l & 15, lk = l >> 4;
    const int row = blockIdx.x * 64 + wv * 16 + lm;
    const int ko  = lk * 8;

    s16x8 ah[4], al[4];
    #pragma unroll
    for (int kb = 0; kb < 4; ++kb) {
        const int k0 = kb * 32;
        const float4 a0 = *(const float4*)(x + row * 128 + k0 + ko);
        const float4 a1 = *(const float4*)(x + row * 128 + k0 + ko + 4);
        const float av[8] = {a0.x, a0.y, a0.z, a0.w, a1.x, a1.y, a1.z, a1.w};
        #pragma unroll
        for (int e = 0; e < 8; ++e) {
            const ushort hh = bf16_rtn(av[e]);
            ah[kb][e] = (short)hh;
            al[kb][e] = (short)bf16_rtn(av[e] - bf16_f32(hh));
        }
    }

    __syncthreads();

    f32x4 acc[4];
    #pragma unroll
    for (int nt = 0; nt < 4; ++nt)
        #pragma unroll
        for (int r = 0; r < 4; ++r) acc[nt][r] = 0.f;

    #pragma unroll
    for (int nt = 0; nt < 4; ++nt) {
        const int n = nt * 16 + lm;
        s16x8 bh[4], bl[4];
        #pragma unroll
        for (int kb = 0; kb < 4; ++kb) {
            const int g = kb * 4 + lk;
            bh[kb] = *(const s16x8*)(&bsh[0][BSW(n, g)]);
            bl[kb] = *(const s16x8*)(&bsh[1][BSW(n, g)]);
        }
        #pragma unroll
        for (int kb = 0; kb < 4; ++kb) {
            acc[nt] = __builtin_amdgcn_mfma_f32_16x16x32_bf16(ah[kb], bh[kb], acc[nt], 0, 0, 0);
            acc[nt] = __builtin_amdgcn_mfma_f32_16x16x32_bf16(ah[kb], bl[kb], acc[nt], 0, 0, 0);
            acc[nt] = __builtin_amdgcn_mfma_f32_16x16x32_bf16(al[kb], bh[kb], acc[nt], 0, 0, 0);
        }
    }

    const int orow0 = blockIdx.x * 64 + wv * 16 + lk * 4;
    #pragma unroll
    for (int nt = 0; nt < 4; ++nt) {
        const int col = y * 64 + nt * 16 + lm;
        if (col < 128) {
            const float b = bq[col];
            #pragma unroll
            for (int r = 0; r < 4; ++r)
                qb[(orow0 + r) * 128 + col] = (acc[nt][r] + b) * SCALE;
        } else {
            const int c2 = col - 128;
            const float b = bkv[c2];
            #pragma unroll
            for (int r = 0; r < 4; ++r)
                kvb[(orow0 + r) * 256 + c2] = bf16_rtn(acc[nt][r] + b);
        }
    }
}

// ---------------------------------------------------------------------------
// LDS-halo attention, 8 lanes/voxel (16 ch each). 256 thr, grid 432.
// Tile 2x4x4 voxels; halo 4x6x6 = 144 rows x 272B (16B pad: bank-uniform).
// Two-stage LDS: K halo -> QK logits (1 shuffle each) -> barrier -> V halo
// -> PV. OOB rows zero == reference zero-padding; no bounds checks in hot
// loops. Emits ao as SINGLE bf16 (error budget ok). LDS 38.25 KB -> 4 blk/CU.
// ---------------------------------------------------------------------------
__global__ __launch_bounds__(256) void attn3d(
    const float* __restrict__ qb, const ushort* __restrict__ kvb,
    ushort* __restrict__ aoh)
{
    __shared__ ushort sk[144 * HSTRIDE];   // 39168 B

    const int t  = threadIdx.x;
    const int b  = blockIdx.x;          // 432 tiles: 12d x 6h x 6w
    const int tw = b % 6, th = (b / 6) % 6, td = b / 36;
    const int d0 = td * 2, h0 = th * 4, w0 = tw * 4;

    const int vox = t >> 3;             // 0..31
    const int q8  = t & 7;              // half-head id: head=q8>>1, half=q8&1
    const int ld = vox >> 4, lh = (vox >> 2) & 3, lw = vox & 3;
    const int n  = ((d0 + ld) * DD3 + (h0 + lh)) * DD3 + (w0 + lw);
    const int choff = q8 * 16;          // channel window [choff, choff+16)

    // ---- q into registers (16 f32) ----
    float qv[16];
    #pragma unroll
    for (int m = 0; m < 4; ++m) {
        const float4 qq = *(const float4*)(qb + n * 128 + choff + m * 4);
        qv[m * 4 + 0] = qq.x; qv[m * 4 + 1] = qq.y;
        qv[m * 4 + 2] = qq.z; qv[m * 4 + 3] = qq.w;
    }

    // ---- stage K halo (144 rows x 256B payload, stride 272B) ----
    #pragma unroll
    for (int p = 0; p < 9; ++p) {
        const int e = p * 256 + t;          // 0..2303
        const int r = e >> 4;               // halo row
        const int c = e & 15;               // 16B chunk
        const int a = r / 36, bb = (r / 6) % 6, cc = r % 6;
        const int gd = d0 - 1 + a, gh = h0 - 1 + bb, gw = w0 - 1 + cc;
        int4 v = {0, 0, 0, 0};
        if ((unsigned)gd < DD3 && (unsigned)gh < DD3 && (unsigned)gw < DD3) {
            const int n2 = (gd * DD3 + gh) * DD3 + gw;
            v = *(const int4*)(kvb + n2 * 256 + c * 8);
        }
        *(int4*)(sk + r * HSTRIDE + c * 8) = v;
    }
    __syncthreads();

    // ---- QK: 27 logits, 1 shuffle each ----
    const int vbase = (ld * 36 + lh * 6 + lw);   // voxel's halo base row
    const ushort* kvoxel = sk + vbase * HSTRIDE + choff;

    float logit[27];
    #pragma unroll
    for (int i = 0; i < 3; ++i)
        #pragma unroll
        for (int j = 0; j < 3; ++j)
            #pragma unroll
            for (int l2 = 0; l2 < 3; ++l2) {
                const int idx = (i * 3 + j) * 3 + l2;
                const ushort* kr = kvoxel + (i * 36 + j * 6 + l2) * HSTRIDE;
                const int4 ka = *(const int4*)(kr);
                const int4 kb2 = *(const int4*)(kr + 8);
                float p = 0.f;
                const int* kwa = (const int*)&ka;
                const int* kwb = (const int*)&kb2;
                #pragma unroll
                for (int m = 0; m < 4; ++m) {
                    const unsigned u = (unsigned)kwa[m];
                    p = fmaf(qv[2 * m],     __uint_as_float(u << 16),        p);
                    p = fmaf(qv[2 * m + 1], __uint_as_float(u & 0xffff0000u), p);
                }
                #pragma unroll
                for (int m = 0; m < 4; ++m) {
                    const unsigned u = (unsigned)kwb[m];
                    p = fmaf(qv[8 + 2 * m],     __uint_as_float(u << 16),        p);
                    p = fmaf(qv[8 + 2 * m + 1], __uint_as_float(u & 0xffff0000u), p);
                }
                p += __shfl_xor(p, 1);   // combine the two half-head partials
                logit[idx] = p;          // exactly 0 for OOB
            }

    // ---- softmax (tree reductions) ----
    float m0;
    {
        float t1[14];
        #pragma unroll
        for (int k = 0; k < 13; ++k) t1[k] = fmaxf(logit[2 * k], logit[2 * k + 1]);
        t1[13] = logit[26];
        float t2[7];
        #pragma unroll
        for (int k = 0; k < 7; ++k) t2[k] = fmaxf(t1[2 * k], t1[2 * k + 1]);
        m0 = fmaxf(fmaxf(fmaxf(t2[0], t2[1]), fmaxf(t2[2], t2[3])),
                   fmaxf(fmaxf(t2[4], t2[5]), t2[6]));
    }
    float s;
    {
        #pragma unroll
        for (int idx = 0; idx < 27; ++idx) logit[idx] = __expf(logit[idx] - m0);
        float t1[14];
        #pragma unroll
        for (int k = 0; k < 13; ++k) t1[k] = logit[2 * k] + logit[2 * k + 1];
        t1[13] = logit[26];
        float t2[7];
        #pragma unroll
        for (int k = 0; k < 7; ++k) t2[k] = t1[2 * k] + t1[2 * k + 1];
        s = ((t2[0] + t2[1]) + (t2[2] + t2[3])) + ((t2[4] + t2[5]) + t2[6]);
    }
    const float inv = 1.f / s;

    __syncthreads();   // all QK reads done; safe to overwrite LDS

    // ---- stage V halo ----
    #pragma unroll
    for (int p = 0; p < 9; ++p) {
        const int e = p * 256 + t;
        const int r = e >> 4;
        const int c = e & 15;
        const int a = r / 36, bb = (r / 6) % 6, cc = r % 6;
        const int gd = d0 - 1 + a, gh = h0 - 1 + bb, gw = w0 - 1 + cc;
        int4 v = {0, 0, 0, 0};
        if ((unsigned)gd < DD3 && (unsigned)gh < DD3 && (unsigned)gw < DD3) {
            const int n2 = (gd * DD3 + gh) * DD3 + gw;
            v = *(const int4*)(kvb + n2 * 256 + 128 + c * 8);
        }
        *(int4*)(sk + r * HSTRIDE + c * 8) = v;
    }
    __syncthreads();

    // ---- PV: accumulate 16 channels ----
    float acc[16];
    #pragma unroll
    for (int m = 0; m < 16; ++m) acc[m] = 0.f;

    #pragma unroll
    for (int i = 0; i < 3; ++i)
        #pragma unroll
        for (int j = 0; j < 3; ++j)
            #pragma unroll
            for (int l2 = 0; l2 < 3; ++l2) {
                const int idx = (i * 3 + j) * 3 + l2;
                const float p = logit[idx];
                const ushort* vr = kvoxel + (i * 36 + j * 6 + l2) * HSTRIDE;
                const int4 va = *(const int4*)(vr);
                const int4 vb2 = *(const int4*)(vr + 8);
                const int* vwa = (const int*)&va;
                const int* vwb = (const int*)&vb2;
                #pragma unroll
                for (int m = 0; m < 4; ++m) {
                    const unsigned u = (unsigned)vwa[m];
                    acc[2 * m]     = fmaf(p, __uint_as_float(u << 16),         acc[2 * m]);
                    acc[2 * m + 1] = fmaf(p, __uint_as_float(u & 0xffff0000u), acc[2 * m + 1]);
                }
                #pragma unroll
                for (int m = 0; m < 4; ++m) {
                    const unsigned u = (unsigned)vwb[m];
                    acc[8 + 2 * m]     = fmaf(p, __uint_as_float(u << 16),         acc[8 + 2 * m]);
                    acc[8 + 2 * m + 1] = fmaf(p, __uint_as_float(u & 0xffff0000u), acc[8 + 2 * m + 1]);
                }
            }

    // ---- normalize + write single-bf16 ao ----
    int pk[8];
    #pragma unroll
    for (int m = 0; m < 8; ++m) {
        const float e0 = acc[2 * m] * inv;
        const float e1 = acc[2 * m + 1] * inv;
        pk[m] = (int)bf16_rtn(e0) | ((int)bf16_rtn(e1) << 16);
    }
    int4 o0 = {pk[0], pk[1], pk[2], pk[3]};
    int4 o1 = {pk[4], pk[5], pk[6], pk[7]};
    *(int4*)(aoh + n * 128 + choff)     = o0;
    *(int4*)(aoh + n * 128 + choff + 8) = o1;
}

// ---------------------------------------------------------------------------
// Projection (single-bf16 A). grid (216, 2), block 256. Wp panel (hi/lo)
// DMA'd from wimg segs 6,7. 2 MFMAs per k-block.
// ---------------------------------------------------------------------------
__global__ __launch_bounds__(256) void proj_fused(
    const ushort* __restrict__ aoh, const ushort* __restrict__ wimg,
    const float* __restrict__ bp, float* __restrict__ out)
{
    __shared__ ushort bsh[2][8192];   // 32 KB

    const int t  = threadIdx.x;
    const int wv = t >> 6, l = t & 63;

    const char* wseg = (const char*)(wimg + (6 + blockIdx.y) * 16384);
    #pragma unroll
    for (int p = 0; p < 8; ++p) {
        const int chunk = (wv * 8 + p) * 1024;
        __builtin_amdgcn_global_load_lds(
            (const __attribute__((address_space(1))) void*)(wseg + chunk + l * 16),
            (__attribute__((address_space(3))) void*)((char*)bsh + chunk),
            16, 0, 0);
    }

    const int lm = l & 15, lk = l >> 4;
    const int row = blockIdx.x * 64 + wv * 16 + lm;
    const int ko  = lk * 8;

    s16x8 ah[4];
    #pragma unroll
    for (int kb = 0; kb < 4; ++kb)
        ah[kb] = *(const s16x8*)(aoh + row * 128 + kb * 32 + ko);

    __syncthreads();

    f32x4 acc[4];
    #pragma unroll
    for (int nt = 0; nt < 4; ++nt)
        #pragma unroll
        for (int r = 0; r < 4; ++r) acc[nt][r] = 0.f;

    #pragma unroll
    for (int nt = 0; nt < 4; ++nt) {
        const int n = nt * 16 + lm;
        s16x8 bh[4], bl[4];
        #pragma unroll
        for (int kb = 0; kb < 4; ++kb) {
            const int g = kb * 4 + lk;
            bh[kb] = *(const s16x8*)(&bsh[0][BSW(n, g)]);
            bl[kb] = *(const s16x8*)(&bsh[1][BSW(n, g)]);
        }
        #pragma unroll
        for (int kb = 0; kb < 4; ++kb) {
            acc[nt] = __builtin_amdgcn_mfma_f32_16x16x32_bf16(ah[kb], bh[kb], acc[nt], 0, 0, 0);
            acc[nt] = __builtin_amdgcn_mfma_f32_16x16x32_bf16(ah[kb], bl[kb], acc[nt], 0, 0, 0);
        }
    }

    const int orow0 = blockIdx.x * 64 + wv * 16 + lk * 4;
    #pragma unroll
    for (int nt = 0; nt < 4; ++nt) {
        const int col = blockIdx.y * 64 + nt * 16 + lm;
        const float b = bp[col];
        #pragma unroll
        for (int r = 0; r < 4; ++r)
            out[(orow0 + r) * 128 + col] = acc[nt][r] + b;
    }
}

extern "C" void kernel_launch(void* const* d_in, const int* in_sizes, int n_in,
                              void* d_out, int out_size, void* d_ws, size_t ws_size,
                              hipStream_t stream) {
    const float* x   = (const float*)d_in[0];
    const float* Wq  = (const float*)d_in[1];
    const float* bq  = (const float*)d_in[2];
    const float* Wkv = (const float*)d_in[3];
    const float* bkv = (const float*)d_in[4];
    const float* Wp  = (const float*)d_in[5];
    const float* bp  = (const float*)d_in[6];
    float* out = (float*)d_out;

    // workspace: qb@0, kvb@7,077,888, aoh@14,155,776, wimg@17,694,720
    char* ws = (char*)d_ws;
    float*  qb   = (float*)(ws);
    ushort* kvb  = (ushort*)(ws + 7077888);
    ushort* aoh  = (ushort*)(ws + 14155776);
    ushort* wimg = (ushort*)(ws + 17694720);

    prep_w<<<64, 256, 0, stream>>>(Wq, Wkv, Wp, wimg);
    dim3 g1(NTOK / 64, 6);
    qkv_fused<<<g1, 256, 0, stream>>>(x, wimg, bq, bkv, qb, kvb);
    attn3d<<<432, 256, 0, stream>>>(qb, kvb, aoh);
    dim3 g2(NTOK / 64, 2);
    proj_fused<<<g2, 256, 0, stream>>>(aoh, wimg, bp, out);
}